// Round 11
// baseline (123.586 us; speedup 1.0000x reference)
//
#include <hip/hip_runtime.h>
#include <hip/hip_bf16.h>

// EdgeNetwork: B=8, N=256, F_IN=64, F_OUT=64, MID=96
// R11 = MEASUREMENT PROBE. Identical kernels to R10; edge_main5 is launched
// 5x with identical args (deterministic, same output each time). Purpose:
// amplify the true edge_main cost 5x to discriminate "kernel ~31us" vs
// "harness floor ~38-39us (268MB poison fills) hiding a ~10us kernel".
// dur ~45-60us  => floor theory (main ~8-11us), restore single launch next.
// dur ~150us+   => kernel-bound theory, attack per-wave stalls next.

#define BATCH 8
#define NN 256
#define FIN 64
#define FOUT 64
#define MIDD 96
#define CPAD 104   // bf16 elems per padded row (208 B)
#define NG 4       // n-values per block

typedef __attribute__((ext_vector_type(8))) short short8;  // 8 bf16
typedef __attribute__((ext_vector_type(4))) float f32x4;
typedef __attribute__((ext_vector_type(2))) float f32x2;

#if __has_builtin(__builtin_amdgcn_exp2f)
#define EXP2F(x) __builtin_amdgcn_exp2f(x)
#else
#define EXP2F(x) exp2f(x)
#endif
#if __has_builtin(__builtin_amdgcn_rcpf)
#define RCPF(x) __builtin_amdgcn_rcpf(x)
#else
#define RCPF(x) (1.0f / (x))
#endif

#define TWO_LOG2E 2.8853900817779268f

__device__ __forceinline__ f32x2 pk_add(f32x2 a, f32x2 b) {
    f32x2 d;
    asm("v_pk_add_f32 %0, %1, %2" : "=v"(d) : "v"(a), "v"(b));
    return d;
}
__device__ __forceinline__ f32x2 pk_fma(f32x2 a, f32x2 b, f32x2 c) {
    f32x2 d;
    asm("v_pk_fma_f32 %0, %1, %2, %3" : "=v"(d) : "v"(a), "v"(b), "v"(c));
    return d;
}

__device__ __forceinline__ unsigned pack_bf16(float lo, float hi) {
    __hip_bfloat162 h2 = __float22bfloat162_rn(make_float2(lo, hi));
    union { __hip_bfloat162 h; unsigned u; } cv; cv.h = h2;
    return cv.u;
}

// ------------- precompute: A (f32), C (bf16 padded), W2T (bf16 padded) -------
__global__ __launch_bounds__(192) void edge_pre(
    const float* __restrict__ node,    // (B,N,64)
    const float* __restrict__ W1,      // (129,96)
    const float* __restrict__ b1,      // (96,)
    const float* __restrict__ W2,      // (96,64)
    float* __restrict__ A,             // (B*N,96) f32
    unsigned short* __restrict__ Cb16, // (B,N,CPAD) bf16
    unsigned short* __restrict__ W2T)  // (64,CPAD) bf16
{
    int blk = blockIdx.x;
    int tid = threadIdx.x;
    if (blk == BATCH * NN) {
        for (int idx = tid; idx < FOUT * CPAD; idx += 192) {
            int c = idx / CPAD, k = idx % CPAD;
            float v = (k < MIDD) ? W2[k * FOUT + c] : 0.f;
            union { __hip_bfloat16 h; unsigned short u; } cv;
            cv.h = __float2bfloat16(v);
            W2T[idx] = cv.u;
        }
        return;
    }
    __shared__ float x[FIN];
    if (tid < FIN) x[tid] = node[(size_t)blk * FIN + tid];
    __syncthreads();
    if (tid < MIDD) {
        int h = tid;
        float s = b1[h];
#pragma unroll
        for (int f = 0; f < FIN; ++f) s = fmaf(x[f], W1[f * MIDD + h], s);
        A[(size_t)blk * MIDD + h] = s;
    } else {
        int h = tid - MIDD;   // 0..95
        float s = 0.f;
#pragma unroll
        for (int f = 0; f < FIN; ++f) s = fmaf(x[f], W1[(FIN + f) * MIDD + h], s);
        union { __hip_bfloat16 hh; unsigned short u; } cv;
        cv.hh = __float2bfloat16(s);
        Cb16[(size_t)blk * CPAD + h] = cv.u;
        if (h < CPAD - MIDD) Cb16[(size_t)blk * CPAD + MIDD + h] = 0;  // pad
    }
}

// ------------- main: LDS-staged C[b], packed math, reg double-buffering ------
__global__ __launch_bounds__(256, 2) void edge_main5(
    const float* __restrict__ edge,          // (B,N,255)
    const float* __restrict__ A,             // (B*N,96)
    const unsigned short* __restrict__ Cb16, // (B,N,CPAD) bf16
    const float* __restrict__ W1,            // row 128 used
    const unsigned short* __restrict__ W2T,  // (64,CPAD) bf16
    const float* __restrict__ b2,            // (64,)
    float* __restrict__ out)                 // (B,N,64)
{
    __shared__ unsigned short sC[NN * CPAD];   // 53248 B; tail reused for reduce

    int blk = blockIdx.x;             // 0..511
    int b = blk >> 6;
    int n0 = (blk & 63) << 2;
    int tid = threadIdx.x;
    int w = tid >> 6, lane = tid & 63;
    int lo16 = lane & 15, hi = lane >> 4;

    // stage C[b] -> LDS, fully coalesced (3328 uint4)
    {
        const uint4* src = (const uint4*)(Cb16 + (size_t)b * NN * CPAD);
        uint4* dst = (uint4*)sC;
#pragma unroll
        for (int i = 0; i < 13; ++i) dst[i * 256 + tid] = src[i * 256 + tid];
    }

    // W1[128] slices as f32x2 pairs: pair p of ks covers k = ks*32+hi*8+2p..+1
    f32x2 W2p[12];
    {
        const float* Wbase = W1 + 128 * MIDD;
#pragma unroll
        for (int ks = 0; ks < 3; ++ks) {
            int k0 = ks * 32 + hi * 8;
            float4 w0 = *(const float4*)(Wbase + k0);
            float4 w1 = *(const float4*)(Wbase + k0 + 4);
            W2p[ks*4+0] = f32x2{w0.x, w0.y};
            W2p[ks*4+1] = f32x2{w0.z, w0.w};
            W2p[ks*4+2] = f32x2{w1.x, w1.y};
            W2p[ks*4+3] = f32x2{w1.z, w1.w};
        }
    }

    // B fragments from global W2T (one-time, L2-resident)
    short8 bf[4][3];
#pragma unroll
    for (int nt = 0; nt < 4; ++nt)
#pragma unroll
        for (int ks = 0; ks < 3; ++ks)
            bf[nt][ks] = *(const short8*)&W2T[(nt * 16 + lo16) * CPAD + ks * 32 + hi * 8];

    float c2[4], corr[4];
#pragma unroll
    for (int nt = 0; nt < 4; ++nt) {
        c2[nt] = TWO_LOG2E * b2[nt * 16 + lo16];
        corr[nt] = 0.5f - RCPF(1.f + EXP2F(c2[nt]));
    }

    __syncthreads();

    float Rs[NG][4];
#pragma unroll
    for (int nl = 0; nl < NG; ++nl)
#pragma unroll
        for (int nt = 0; nt < 4; ++nt) Rs[nl][nt] = 0.f;

    // A-row double buffer (global loads issued one nl ahead)
    float4 Ab[6];
    {
        const float* Abase = A + (size_t)((b << 8) + n0) * MIDD;
#pragma unroll
        for (int ks = 0; ks < 3; ++ks) {
            int k0 = ks * 32 + hi * 8;
            Ab[ks*2+0] = *(const float4*)(Abase + k0);
            Ab[ks*2+1] = *(const float4*)(Abase + k0 + 4);
        }
    }

#pragma unroll 1
    for (int nl = 0; nl < NG; ++nl) {
        int n = n0 + nl;
        int bn = (b << 8) + n;

        // unpack current A into pairs, then issue next nl's loads
        f32x2 A2[12];
#pragma unroll
        for (int ks = 0; ks < 3; ++ks) {
            float4 a0 = Ab[ks*2+0], a1 = Ab[ks*2+1];
            A2[ks*4+0] = f32x2{a0.x, a0.y};
            A2[ks*4+1] = f32x2{a0.z, a0.w};
            A2[ks*4+2] = f32x2{a1.x, a1.y};
            A2[ks*4+3] = f32x2{a1.z, a1.w};
        }
        if (nl < NG - 1) {
            const float* Abase = A + (size_t)(bn + 1) * MIDD;
#pragma unroll
            for (int ks = 0; ks < 3; ++ks) {
                int k0 = ks * 32 + hi * 8;
                Ab[ks*2+0] = *(const float4*)(Abase + k0);
                Ab[ks*2+1] = *(const float4*)(Abase + k0 + 4);
            }
        }

        const float* eg = edge + (size_t)bn * (NN - 1);
        // prefetch all 4 chunks' edge values
        float ev[4];
#pragma unroll
        for (int c = 0; c < 4; ++c) {
            int m = c * 64 + w * 16 + lo16;
            ev[c] = eg[m < NN - 1 ? m : NN - 2];
        }

        // C-slice register double buffer: q = current chunk's 3 b128 reads
        uint4 q0, q1, q2;
        {
            int m = w * 16 + lo16;
            int j = m + (m >= n);
            const unsigned short* crow = &sC[j * CPAD + hi * 8];
            q0 = *(const uint4*)(crow);
            q1 = *(const uint4*)(crow + 32);
            q2 = *(const uint4*)(crow + 64);
        }

#pragma unroll
        for (int chunk = 0; chunk < 4; ++chunk) {
            uint4 n0q, n1q, n2q;
            if (chunk < 3) {
                int mn = (chunk + 1) * 64 + w * 16 + lo16;
                int jn = mn + (mn >= n);
                if (chunk + 1 == 3) jn = (jn > 255) ? 255 : jn;
                const unsigned short* crow = &sC[jn * CPAD + hi * 8];
                n0q = *(const uint4*)(crow);
                n1q = *(const uint4*)(crow + 32);
                n2q = *(const uint4*)(crow + 64);
            }

            f32x2 e2 = f32x2{ev[chunk], ev[chunk]};
            uint4 qs[3] = {q0, q1, q2};

            short8 af[3];
#pragma unroll
            for (int ks = 0; ks < 3; ++ks) {
                unsigned uu[4] = {qs[ks].x, qs[ks].y, qs[ks].z, qs[ks].w};
                unsigned ro[4];
#pragma unroll
                for (int p = 0; p < 4; ++p) {
                    f32x2 c;
                    c.x = __uint_as_float(uu[p] << 16);
                    c.y = __uint_as_float(uu[p] & 0xFFFF0000u);
                    f32x2 s = pk_add(A2[ks*4+p], c);
                    f32x2 h = pk_fma(e2, W2p[ks*4+p], s);
                    ro[p] = pack_bf16(fmaxf(h.x, 0.f), fmaxf(h.y, 0.f));
                }
                union { unsigned u[4]; short8 s8; } cv;
                cv.u[0] = ro[0]; cv.u[1] = ro[1]; cv.u[2] = ro[2]; cv.u[3] = ro[3];
                af[ks] = cv.s8;
            }

            // invalid slot: m=255 -> row lo16==15 of wave 3, chunk 3 only
            if (chunk == 3 && w == 3 && lo16 == 15) {
                af[0] = (short8)0; af[1] = (short8)0; af[2] = (short8)0;
            }

            f32x4 acc[4] = {{0.f,0.f,0.f,0.f},{0.f,0.f,0.f,0.f},
                            {0.f,0.f,0.f,0.f},{0.f,0.f,0.f,0.f}};
#pragma unroll
            for (int ks = 0; ks < 3; ++ks)
#pragma unroll
                for (int nt = 0; nt < 4; ++nt)
                    acc[nt] = __builtin_amdgcn_mfma_f32_16x16x32_bf16(
                        af[ks], bf[nt][ks], acc[nt], 0, 0, 0);

#pragma unroll
            for (int nt = 0; nt < 4; ++nt)
#pragma unroll
                for (int r4 = 0; r4 < 4; ++r4) {
                    float arg = fmaf(acc[nt][r4], TWO_LOG2E, c2[nt]);
                    Rs[nl][nt] += RCPF(1.f + EXP2F(arg));
                }

            if (chunk < 3) { q0 = n0q; q1 = n1q; q2 = n2q; }
        }

        // invalid slot correction (D-row 15 = lanes hi==3, wave 3)
        if (w == 3 && hi == 3) {
#pragma unroll
            for (int nt = 0; nt < 4; ++nt) Rs[nl][nt] += corr[nt];
        }
    }

    // ---- final reduction: overlay on sC (all sC reads are done) ----
    __syncthreads();
    float* s_red = (float*)sC;   // [NG][4 waves][64] = 4 KB
#pragma unroll
    for (int nl = 0; nl < NG; ++nl)
#pragma unroll
        for (int nt = 0; nt < 4; ++nt) {
            float v = Rs[nl][nt];
            v += __shfl_xor(v, 16);
            v += __shfl_xor(v, 32);
            Rs[nl][nt] = v;
        }
    if (hi == 0) {
#pragma unroll
        for (int nl = 0; nl < NG; ++nl)
#pragma unroll
            for (int nt = 0; nt < 4; ++nt)
                s_red[(nl * 4 + w) * 64 + nt * 16 + lo16] = Rs[nl][nt];
    }
    __syncthreads();
    {
        int onl = tid >> 6, oo = tid & 63;   // 256 threads = 4 nl x 64 cols
        float t = s_red[(onl * 4 + 0) * 64 + oo] + s_red[(onl * 4 + 1) * 64 + oo]
                + s_red[(onl * 4 + 2) * 64 + oo] + s_red[(onl * 4 + 3) * 64 + oo];
        out[(size_t)((b << 8) + n0 + onl) * FOUT + oo] = fmaf(-2.f, t, 256.f);
    }
}

extern "C" void kernel_launch(void* const* d_in, const int* in_sizes, int n_in,
                              void* d_out, int out_size, void* d_ws, size_t ws_size,
                              hipStream_t stream) {
    const float* inp_node = (const float*)d_in[0];  // (8,256,64)
    const float* inp_edge = (const float*)d_in[1];  // (8,256,255)
    const float* W1       = (const float*)d_in[2];  // (129,96)
    const float* b1       = (const float*)d_in[3];  // (96,)
    const float* W2       = (const float*)d_in[4];  // (96,64)
    const float* b2       = (const float*)d_in[5];  // (64,)
    float* out            = (float*)d_out;          // (8,256,64)

    float* A = (float*)d_ws;                                        // 2048*96 f32
    unsigned short* Cb16 = (unsigned short*)(A + (size_t)BATCH * NN * MIDD); // 2048*CPAD bf16
    unsigned short* W2T  = Cb16 + (size_t)BATCH * NN * CPAD;        // 64*CPAD bf16

    edge_pre<<<BATCH * NN + 1, 192, 0, stream>>>(inp_node, W1, b1, W2, A, Cb16, W2T);
    // PROBE: 5 identical launches. Deterministic (same inputs -> same out each
    // time); amplifies true edge_main cost 5x against the suspected ~39us
    // harness-fill floor.
    for (int rep = 0; rep < 5; ++rep)
        edge_main5<<<BATCH * (NN / NG), 256, 0, stream>>>(inp_edge, A, Cb16, W1, W2T, b2, out);
}

// Round 13
// 37.637 us; speedup vs baseline: 3.2836x; 3.2836x over previous
//
#include <hip/hip_runtime.h>
#include <hip/hip_bf16.h>

// EdgeNetwork: B=8, N=256, F_IN=64, F_OUT=64, MID=96
// out[b,n,o] = sum_m tanh( relu( [x_n, x_j(m), e_{b,n,m}] @ W1 + b1 ) @ W2 + b2 )[o]
// H[m,:] = A[b,n,:] + C[b,j(m),:] + e[m]*W1[128,:],  j = m + (m>=n)
// R12: cold-replay latency attack. Harness reset evicts L2 every timed replay
// (268MB poison fills) -> first main launch pays ~10us of serialized HBM
// misses. Fix: issue nl0's e+A loads BEFORE sC staging (misses overlap the
// stage barrier), double-buffer e one nl ahead (A already was). edge_pre dots
// get 4 independent accumulators (was a 64-deep serial FMA chain).
// tanh(v) = 1 - 2r, r = 1/(1+exp(2v));  out = 256 - 2*sum(r), invalid -> 0.5.

#define BATCH 8
#define NN 256
#define FIN 64
#define FOUT 64
#define MIDD 96
#define CPAD 104   // bf16 elems per padded row (208 B)
#define NG 4       // n-values per block

typedef __attribute__((ext_vector_type(8))) short short8;  // 8 bf16
typedef __attribute__((ext_vector_type(4))) float f32x4;
typedef __attribute__((ext_vector_type(2))) float f32x2;

#if __has_builtin(__builtin_amdgcn_exp2f)
#define EXP2F(x) __builtin_amdgcn_exp2f(x)
#else
#define EXP2F(x) exp2f(x)
#endif
#if __has_builtin(__builtin_amdgcn_rcpf)
#define RCPF(x) __builtin_amdgcn_rcpf(x)
#else
#define RCPF(x) (1.0f / (x))
#endif

#define TWO_LOG2E 2.8853900817779268f

__device__ __forceinline__ f32x2 pk_add(f32x2 a, f32x2 b) {
    f32x2 d;
    asm("v_pk_add_f32 %0, %1, %2" : "=v"(d) : "v"(a), "v"(b));
    return d;
}
__device__ __forceinline__ f32x2 pk_fma(f32x2 a, f32x2 b, f32x2 c) {
    f32x2 d;
    asm("v_pk_fma_f32 %0, %1, %2, %3" : "=v"(d) : "v"(a), "v"(b), "v"(c));
    return d;
}

__device__ __forceinline__ unsigned pack_bf16(float lo, float hi) {
    __hip_bfloat162 h2 = __float22bfloat162_rn(make_float2(lo, hi));
    union { __hip_bfloat162 h; unsigned u; } cv; cv.h = h2;
    return cv.u;
}

// ------------- precompute: A (f32), C (bf16 padded), W2T (bf16 padded) -------
__global__ __launch_bounds__(192) void edge_pre(
    const float* __restrict__ node,    // (B,N,64)
    const float* __restrict__ W1,      // (129,96)
    const float* __restrict__ b1,      // (96,)
    const float* __restrict__ W2,      // (96,64)
    float* __restrict__ A,             // (B*N,96) f32
    unsigned short* __restrict__ Cb16, // (B,N,CPAD) bf16
    unsigned short* __restrict__ W2T)  // (64,CPAD) bf16
{
    int blk = blockIdx.x;
    int tid = threadIdx.x;
    if (blk == BATCH * NN) {
        for (int idx = tid; idx < FOUT * CPAD; idx += 192) {
            int c = idx / CPAD, k = idx % CPAD;
            float v = (k < MIDD) ? W2[k * FOUT + c] : 0.f;
            union { __hip_bfloat16 h; unsigned short u; } cv;
            cv.h = __float2bfloat16(v);
            W2T[idx] = cv.u;
        }
        return;
    }
    __shared__ float x[FIN];
    if (tid < FIN) x[tid] = node[(size_t)blk * FIN + tid];
    __syncthreads();
    if (tid < MIDD) {
        int h = tid;
        float a0 = 0.f, a1 = 0.f, a2 = 0.f, a3 = 0.f;
#pragma unroll
        for (int f = 0; f < FIN; f += 4) {
            a0 = fmaf(x[f+0], W1[(f+0) * MIDD + h], a0);
            a1 = fmaf(x[f+1], W1[(f+1) * MIDD + h], a1);
            a2 = fmaf(x[f+2], W1[(f+2) * MIDD + h], a2);
            a3 = fmaf(x[f+3], W1[(f+3) * MIDD + h], a3);
        }
        A[(size_t)blk * MIDD + h] = (a0 + a1) + (a2 + a3) + b1[h];
    } else {
        int h = tid - MIDD;   // 0..95
        float a0 = 0.f, a1 = 0.f, a2 = 0.f, a3 = 0.f;
#pragma unroll
        for (int f = 0; f < FIN; f += 4) {
            a0 = fmaf(x[f+0], W1[(FIN + f+0) * MIDD + h], a0);
            a1 = fmaf(x[f+1], W1[(FIN + f+1) * MIDD + h], a1);
            a2 = fmaf(x[f+2], W1[(FIN + f+2) * MIDD + h], a2);
            a3 = fmaf(x[f+3], W1[(FIN + f+3) * MIDD + h], a3);
        }
        float s = (a0 + a1) + (a2 + a3);
        union { __hip_bfloat16 hh; unsigned short u; } cv;
        cv.hh = __float2bfloat16(s);
        Cb16[(size_t)blk * CPAD + h] = cv.u;
        if (h < CPAD - MIDD) Cb16[(size_t)blk * CPAD + MIDD + h] = 0;  // pad
    }
}

// ------------- main: LDS-staged C[b], cold-loads hoisted, e/A dbuf -----------
__global__ __launch_bounds__(256, 2) void edge_main6(
    const float* __restrict__ edge,          // (B,N,255)
    const float* __restrict__ A,             // (B*N,96)
    const unsigned short* __restrict__ Cb16, // (B,N,CPAD) bf16
    const float* __restrict__ W1,            // row 128 used
    const unsigned short* __restrict__ W2T,  // (64,CPAD) bf16
    const float* __restrict__ b2,            // (64,)
    float* __restrict__ out)                 // (B,N,64)
{
    __shared__ unsigned short sC[NN * CPAD];   // 53248 B; tail reused for reduce

    int blk = blockIdx.x;             // 0..511
    int b = blk >> 6;
    int n0 = (blk & 63) << 2;
    int tid = threadIdx.x;
    int w = tid >> 6, lane = tid & 63;
    int lo16 = lane & 15, hi = lane >> 4;

    // ---- issue nl0's cold loads FIRST (misses overlap staging barrier) ----
    float evc[4];
    {
        const float* eg0 = edge + (size_t)((b << 8) + n0) * (NN - 1);
#pragma unroll
        for (int c = 0; c < 4; ++c) {
            int m = c * 64 + w * 16 + lo16;
            evc[c] = eg0[m < NN - 1 ? m : NN - 2];
        }
    }
    float4 Ab[6];
    {
        const float* Abase = A + (size_t)((b << 8) + n0) * MIDD;
#pragma unroll
        for (int ks = 0; ks < 3; ++ks) {
            int k0 = ks * 32 + hi * 8;
            Ab[ks*2+0] = *(const float4*)(Abase + k0);
            Ab[ks*2+1] = *(const float4*)(Abase + k0 + 4);
        }
    }

    // stage C[b] -> LDS, fully coalesced (3328 uint4)
    {
        const uint4* src = (const uint4*)(Cb16 + (size_t)b * NN * CPAD);
        uint4* dst = (uint4*)sC;
#pragma unroll
        for (int i = 0; i < 13; ++i) dst[i * 256 + tid] = src[i * 256 + tid];
    }

    // W1[128] slices as f32x2 pairs
    f32x2 W2p[12];
    {
        const float* Wbase = W1 + 128 * MIDD;
#pragma unroll
        for (int ks = 0; ks < 3; ++ks) {
            int k0 = ks * 32 + hi * 8;
            float4 w0 = *(const float4*)(Wbase + k0);
            float4 w1 = *(const float4*)(Wbase + k0 + 4);
            W2p[ks*4+0] = f32x2{w0.x, w0.y};
            W2p[ks*4+1] = f32x2{w0.z, w0.w};
            W2p[ks*4+2] = f32x2{w1.x, w1.y};
            W2p[ks*4+3] = f32x2{w1.z, w1.w};
        }
    }

    // B fragments from global W2T (one-time, L2-resident)
    short8 bf[4][3];
#pragma unroll
    for (int nt = 0; nt < 4; ++nt)
#pragma unroll
        for (int ks = 0; ks < 3; ++ks)
            bf[nt][ks] = *(const short8*)&W2T[(nt * 16 + lo16) * CPAD + ks * 32 + hi * 8];

    float c2[4], corr[4];
#pragma unroll
    for (int nt = 0; nt < 4; ++nt) {
        c2[nt] = TWO_LOG2E * b2[nt * 16 + lo16];
        corr[nt] = 0.5f - RCPF(1.f + EXP2F(c2[nt]));
    }

    __syncthreads();

    float Rs[NG][4];
#pragma unroll
    for (int nl = 0; nl < NG; ++nl)
#pragma unroll
        for (int nt = 0; nt < 4; ++nt) Rs[nl][nt] = 0.f;

#pragma unroll 1
    for (int nl = 0; nl < NG; ++nl) {
        int n = n0 + nl;
        int bn = (b << 8) + n;

        // unpack current A into pairs, then issue next nl's A loads
        f32x2 A2[12];
#pragma unroll
        for (int ks = 0; ks < 3; ++ks) {
            float4 a0 = Ab[ks*2+0], a1 = Ab[ks*2+1];
            A2[ks*4+0] = f32x2{a0.x, a0.y};
            A2[ks*4+1] = f32x2{a0.z, a0.w};
            A2[ks*4+2] = f32x2{a1.x, a1.y};
            A2[ks*4+3] = f32x2{a1.z, a1.w};
        }
        if (nl < NG - 1) {
            const float* Abase = A + (size_t)(bn + 1) * MIDD;
#pragma unroll
            for (int ks = 0; ks < 3; ++ks) {
                int k0 = ks * 32 + hi * 8;
                Ab[ks*2+0] = *(const float4*)(Abase + k0);
                Ab[ks*2+1] = *(const float4*)(Abase + k0 + 4);
            }
        }

        // current e values; issue next nl's e loads
        float ev[4];
#pragma unroll
        for (int c = 0; c < 4; ++c) ev[c] = evc[c];
        if (nl < NG - 1) {
            const float* egn = edge + (size_t)(bn + 1) * (NN - 1);
#pragma unroll
            for (int c = 0; c < 4; ++c) {
                int m = c * 64 + w * 16 + lo16;
                evc[c] = egn[m < NN - 1 ? m : NN - 2];
            }
        }

        // C-slice register double buffer: q = current chunk's 3 b128 reads
        uint4 q0, q1, q2;
        {
            int m = w * 16 + lo16;
            int j = m + (m >= n);
            const unsigned short* crow = &sC[j * CPAD + hi * 8];
            q0 = *(const uint4*)(crow);
            q1 = *(const uint4*)(crow + 32);
            q2 = *(const uint4*)(crow + 64);
        }

#pragma unroll
        for (int chunk = 0; chunk < 4; ++chunk) {
            uint4 n0q, n1q, n2q;
            if (chunk < 3) {
                int mn = (chunk + 1) * 64 + w * 16 + lo16;
                int jn = mn + (mn >= n);
                if (chunk + 1 == 3) jn = (jn > 255) ? 255 : jn;
                const unsigned short* crow = &sC[jn * CPAD + hi * 8];
                n0q = *(const uint4*)(crow);
                n1q = *(const uint4*)(crow + 32);
                n2q = *(const uint4*)(crow + 64);
            }

            f32x2 e2 = f32x2{ev[chunk], ev[chunk]};
            uint4 qs[3] = {q0, q1, q2};

            short8 af[3];
#pragma unroll
            for (int ks = 0; ks < 3; ++ks) {
                unsigned uu[4] = {qs[ks].x, qs[ks].y, qs[ks].z, qs[ks].w};
                unsigned ro[4];
#pragma unroll
                for (int p = 0; p < 4; ++p) {
                    f32x2 c;
                    c.x = __uint_as_float(uu[p] << 16);
                    c.y = __uint_as_float(uu[p] & 0xFFFF0000u);
                    f32x2 s = pk_add(A2[ks*4+p], c);
                    f32x2 h = pk_fma(e2, W2p[ks*4+p], s);
                    ro[p] = pack_bf16(fmaxf(h.x, 0.f), fmaxf(h.y, 0.f));
                }
                union { unsigned u[4]; short8 s8; } cv;
                cv.u[0] = ro[0]; cv.u[1] = ro[1]; cv.u[2] = ro[2]; cv.u[3] = ro[3];
                af[ks] = cv.s8;
            }

            // invalid slot: m=255 -> row lo16==15 of wave 3, chunk 3 only
            if (chunk == 3 && w == 3 && lo16 == 15) {
                af[0] = (short8)0; af[1] = (short8)0; af[2] = (short8)0;
            }

            f32x4 acc[4] = {{0.f,0.f,0.f,0.f},{0.f,0.f,0.f,0.f},
                            {0.f,0.f,0.f,0.f},{0.f,0.f,0.f,0.f}};
#pragma unroll
            for (int ks = 0; ks < 3; ++ks)
#pragma unroll
                for (int nt = 0; nt < 4; ++nt)
                    acc[nt] = __builtin_amdgcn_mfma_f32_16x16x32_bf16(
                        af[ks], bf[nt][ks], acc[nt], 0, 0, 0);

#pragma unroll
            for (int nt = 0; nt < 4; ++nt)
#pragma unroll
                for (int r4 = 0; r4 < 4; ++r4) {
                    float arg = fmaf(acc[nt][r4], TWO_LOG2E, c2[nt]);
                    Rs[nl][nt] += RCPF(1.f + EXP2F(arg));
                }

            if (chunk < 3) { q0 = n0q; q1 = n1q; q2 = n2q; }
        }

        // invalid slot correction (D-row 15 = lanes hi==3, wave 3)
        if (w == 3 && hi == 3) {
#pragma unroll
            for (int nt = 0; nt < 4; ++nt) Rs[nl][nt] += corr[nt];
        }
    }

    // ---- final reduction: overlay on sC (all sC reads are done) ----
    __syncthreads();
    float* s_red = (float*)sC;   // [NG][4 waves][64] = 4 KB
#pragma unroll
    for (int nl = 0; nl < NG; ++nl)
#pragma unroll
        for (int nt = 0; nt < 4; ++nt) {
            float v = Rs[nl][nt];
            v += __shfl_xor(v, 16);
            v += __shfl_xor(v, 32);
            Rs[nl][nt] = v;
        }
    if (hi == 0) {
#pragma unroll
        for (int nl = 0; nl < NG; ++nl)
#pragma unroll
            for (int nt = 0; nt < 4; ++nt)
                s_red[(nl * 4 + w) * 64 + nt * 16 + lo16] = Rs[nl][nt];
    }
    __syncthreads();
    {
        int onl = tid >> 6, oo = tid & 63;   // 256 threads = 4 nl x 64 cols
        float t = s_red[(onl * 4 + 0) * 64 + oo] + s_red[(onl * 4 + 1) * 64 + oo]
                + s_red[(onl * 4 + 2) * 64 + oo] + s_red[(onl * 4 + 3) * 64 + oo];
        out[(size_t)((b << 8) + n0 + onl) * FOUT + oo] = fmaf(-2.f, t, 256.f);
    }
}

extern "C" void kernel_launch(void* const* d_in, const int* in_sizes, int n_in,
                              void* d_out, int out_size, void* d_ws, size_t ws_size,
                              hipStream_t stream) {
    const float* inp_node = (const float*)d_in[0];  // (8,256,64)
    const float* inp_edge = (const float*)d_in[1];  // (8,256,255)
    const float* W1       = (const float*)d_in[2];  // (129,96)
    const float* b1       = (const float*)d_in[3];  // (96,)
    const float* W2       = (const float*)d_in[4];  // (96,64)
    const float* b2       = (const float*)d_in[5];  // (64,)
    float* out            = (float*)d_out;          // (8,256,64)

    float* A = (float*)d_ws;                                        // 2048*96 f32
    unsigned short* Cb16 = (unsigned short*)(A + (size_t)BATCH * NN * MIDD); // 2048*CPAD bf16
    unsigned short* W2T  = Cb16 + (size_t)BATCH * NN * CPAD;        // 64*CPAD bf16

    edge_pre<<<BATCH * NN + 1, 192, 0, stream>>>(inp_node, W1, b1, W2, A, Cb16, W2T);
    edge_main6<<<BATCH * (NN / NG), 256, 0, stream>>>(inp_edge, A, Cb16, W1, W2T, b2, out);
}

// Round 14
// 33.115 us; speedup vs baseline: 3.7321x; 1.1366x over previous
//
#include <hip/hip_runtime.h>
#include <hip/hip_bf16.h>

// EdgeNetwork: B=8, N=256, F_IN=64, F_OUT=64, MID=96
// out[b,n,o] = sum_m tanh( relu( [x_n, x_j(m), e_{b,n,m}] @ W1 + b1 ) @ W2 + b2 )[o]
// H[m,:] = A[b,n,:] + C[b,j(m),:] + e[m]*W1[128,:],  j = m + (m>=n)
// R14: FULL FUSION, single kernel. Each block (b, n-quad):
//   phase B: C[b] = node[b] @ W1[64:128] via MFMA, written bf16 -> sC (redundant
//            per 64 blocks/b, ~1us on matrix pipe — removes edge_pre + its
//            cold A/C/W2T round-trip + one launch boundary entirely)
//   phase C: A rows n0..n0+3 via VALU from LDS-staged x rows
//   main loop: as R13 (LDS C reads, packed f32 H-build, bf16 MFMA, r-sum)
// tanh(v) = 1 - 2r, r = 1/(1+exp(2v));  out = 256 - 2*sum(r), invalid -> 0.5.

#define BATCH 8
#define NN 256
#define FIN 64
#define FOUT 64
#define MIDD 96
#define CPAD 104   // bf16 elems per padded sC row (208 B)
#define NG 4       // n-values per block

typedef __attribute__((ext_vector_type(8))) short short8;  // 8 bf16
typedef __attribute__((ext_vector_type(4))) float f32x4;
typedef __attribute__((ext_vector_type(2))) float f32x2;

#if __has_builtin(__builtin_amdgcn_exp2f)
#define EXP2F(x) __builtin_amdgcn_exp2f(x)
#else
#define EXP2F(x) exp2f(x)
#endif
#if __has_builtin(__builtin_amdgcn_rcpf)
#define RCPF(x) __builtin_amdgcn_rcpf(x)
#else
#define RCPF(x) (1.0f / (x))
#endif

#define TWO_LOG2E 2.8853900817779268f

__device__ __forceinline__ f32x2 pk_add(f32x2 a, f32x2 b) {
    f32x2 d;
    asm("v_pk_add_f32 %0, %1, %2" : "=v"(d) : "v"(a), "v"(b));
    return d;
}
__device__ __forceinline__ f32x2 pk_fma(f32x2 a, f32x2 b, f32x2 c) {
    f32x2 d;
    asm("v_pk_fma_f32 %0, %1, %2, %3" : "=v"(d) : "v"(a), "v"(b), "v"(c));
    return d;
}

__device__ __forceinline__ unsigned pack_bf16(float lo, float hi) {
    __hip_bfloat162 h2 = __float22bfloat162_rn(make_float2(lo, hi));
    union { __hip_bfloat162 h; unsigned u; } cv; cv.h = h2;
    return cv.u;
}
__device__ __forceinline__ unsigned short bf16_bits(float v) {
    union { __hip_bfloat16 h; unsigned short u; } cv;
    cv.h = __float2bfloat16(v);
    return cv.u;
}

// ---------------- single fused kernel -----------------------------------------
__global__ __launch_bounds__(256, 2) void edge_fused(
    const float* __restrict__ node,   // (B,N,64)
    const float* __restrict__ edge,   // (B,N,255)
    const float* __restrict__ W1,     // (129,96)
    const float* __restrict__ b1,     // (96,)
    const float* __restrict__ W2,     // (96,64)
    const float* __restrict__ b2,     // (64,)
    float* __restrict__ out)          // (B,N,64)
{
    __shared__ unsigned short sC[NN * CPAD];   // 53248 B; tail reused for reduce
    __shared__ float sX[NG][FIN];              // 1024 B: x rows n0..n0+3
    __shared__ float sA[NG][MIDD];             // 1536 B: A rows n0..n0+3

    int blk = blockIdx.x;             // 0..511
    int b = blk >> 6;
    int n0 = (blk & 63) << 2;
    int tid = threadIdx.x;
    int w = tid >> 6, lane = tid & 63;
    int lo16 = lane & 15, hi = lane >> 4;

    // ---- e prefetch (nl0), x-row staging ----
    float evc[4];
    {
        const float* eg0 = edge + (size_t)((b << 8) + n0) * (NN - 1);
#pragma unroll
        for (int c = 0; c < 4; ++c) {
            int m = c * 64 + w * 16 + lo16;
            evc[c] = eg0[m < NN - 1 ? m : NN - 2];
        }
    }
    sX[w][lane] = node[((size_t)b * NN + n0 + w) * FIN + lane];

    // ---- phase B: C[b] = node[b] @ W1[64:128] via MFMA -> sC (bf16) ----
    {
        // B-fragments of W1b: wb[ks2][ct], elem i = W1[64+ks2*32+hi*8+i][ct*16+lo16]
        short8 wb[2][6];
#pragma unroll
        for (int ks2 = 0; ks2 < 2; ++ks2)
#pragma unroll
            for (int ct = 0; ct < 6; ++ct) {
                float v[8];
#pragma unroll
                for (int i = 0; i < 8; ++i)
                    v[i] = W1[(size_t)(FIN + ks2 * 32 + hi * 8 + i) * MIDD + ct * 16 + lo16];
                union { unsigned u[4]; short8 s8; } cv;
                cv.u[0] = pack_bf16(v[0], v[1]);
                cv.u[1] = pack_bf16(v[2], v[3]);
                cv.u[2] = pack_bf16(v[4], v[5]);
                cv.u[3] = pack_bf16(v[6], v[7]);
                wb[ks2][ct] = cv.s8;
            }

        const float* nb = node + (size_t)b * NN * FIN;
#pragma unroll
        for (int rt4 = 0; rt4 < 4; ++rt4) {
            int rtile = rt4 * 4 + w;          // 0..15, unique per wave
            int row = rtile * 16 + lo16;
            // A-fragments: xa[ks2] elem i = node[b][row][ks2*32+hi*8+i]
            short8 xa[2];
#pragma unroll
            for (int ks2 = 0; ks2 < 2; ++ks2) {
                const float* xr = nb + (size_t)row * FIN + ks2 * 32 + hi * 8;
                float4 x0 = *(const float4*)(xr);
                float4 x1 = *(const float4*)(xr + 4);
                union { unsigned u[4]; short8 s8; } cv;
                cv.u[0] = pack_bf16(x0.x, x0.y);
                cv.u[1] = pack_bf16(x0.z, x0.w);
                cv.u[2] = pack_bf16(x1.x, x1.y);
                cv.u[3] = pack_bf16(x1.z, x1.w);
                xa[ks2] = cv.s8;
            }
            f32x4 acc6[6] = {{0.f,0.f,0.f,0.f},{0.f,0.f,0.f,0.f},{0.f,0.f,0.f,0.f},
                             {0.f,0.f,0.f,0.f},{0.f,0.f,0.f,0.f},{0.f,0.f,0.f,0.f}};
#pragma unroll
            for (int ks2 = 0; ks2 < 2; ++ks2)
#pragma unroll
                for (int ct = 0; ct < 6; ++ct)
                    acc6[ct] = __builtin_amdgcn_mfma_f32_16x16x32_bf16(
                        xa[ks2], wb[ks2][ct], acc6[ct], 0, 0, 0);
            // D: row = rtile*16 + hi*4 + r, col = ct*16 + lo16
#pragma unroll
            for (int ct = 0; ct < 6; ++ct)
#pragma unroll
                for (int r = 0; r < 4; ++r)
                    sC[(size_t)(rtile * 16 + hi * 4 + r) * CPAD + ct * 16 + lo16] =
                        bf16_bits(acc6[ct][r]);
        }
    }

    __syncthreads();   // sX + sC ready

    // ---- phase C: A rows via VALU: sA[nl][c] = x_{n0+nl} . W1[:64,c] + b1[c] ----
    {
#pragma unroll
        for (int it = 0; it < 2; ++it) {
            int idx = it * 256 + tid;
            if (idx < NG * MIDD) {
                int nl = idx / MIDD, c = idx % MIDD;
                float a0 = 0.f, a1 = 0.f;
#pragma unroll
                for (int f = 0; f < FIN; f += 2) {
                    a0 = fmaf(sX[nl][f],     W1[(size_t)f * MIDD + c],       a0);
                    a1 = fmaf(sX[nl][f + 1], W1[(size_t)(f + 1) * MIDD + c], a1);
                }
                sA[nl][c] = a0 + a1 + b1[c];
            }
        }
    }

    // ---- per-lane constants for the main loop (global reads only) ----
    f32x2 W2p[12];   // W1[128] slices as f32 pairs
    {
        const float* Wbase = W1 + 128 * MIDD;
#pragma unroll
        for (int ks = 0; ks < 3; ++ks) {
            int k0 = ks * 32 + hi * 8;
            float4 w0 = *(const float4*)(Wbase + k0);
            float4 w1 = *(const float4*)(Wbase + k0 + 4);
            W2p[ks*4+0] = f32x2{w0.x, w0.y};
            W2p[ks*4+1] = f32x2{w0.z, w0.w};
            W2p[ks*4+2] = f32x2{w1.x, w1.y};
            W2p[ks*4+3] = f32x2{w1.z, w1.w};
        }
    }
    // W2 B-fragments: bf[nt][ks] elem i = W2[ks*32+hi*8+i][nt*16+lo16]
    short8 bf[4][3];
#pragma unroll
    for (int nt = 0; nt < 4; ++nt)
#pragma unroll
        for (int ks = 0; ks < 3; ++ks) {
            float v[8];
#pragma unroll
            for (int i = 0; i < 8; ++i)
                v[i] = W2[(size_t)(ks * 32 + hi * 8 + i) * FOUT + nt * 16 + lo16];
            union { unsigned u[4]; short8 s8; } cv;
            cv.u[0] = pack_bf16(v[0], v[1]);
            cv.u[1] = pack_bf16(v[2], v[3]);
            cv.u[2] = pack_bf16(v[4], v[5]);
            cv.u[3] = pack_bf16(v[6], v[7]);
            bf[nt][ks] = cv.s8;
        }

    float c2[4], corr[4];
#pragma unroll
    for (int nt = 0; nt < 4; ++nt) {
        c2[nt] = TWO_LOG2E * b2[nt * 16 + lo16];
        corr[nt] = 0.5f - RCPF(1.f + EXP2F(c2[nt]));
    }

    __syncthreads();   // sA ready

    float Rs[NG][4];
#pragma unroll
    for (int nl = 0; nl < NG; ++nl)
#pragma unroll
        for (int nt = 0; nt < 4; ++nt) Rs[nl][nt] = 0.f;

#pragma unroll 1
    for (int nl = 0; nl < NG; ++nl) {
        int n = n0 + nl;
        int bn = (b << 8) + n;

        // A slices from sA (broadcast LDS reads)
        f32x2 A2[12];
#pragma unroll
        for (int ks = 0; ks < 3; ++ks) {
            const float* ap = &sA[nl][ks * 32 + hi * 8];
            float4 a0 = *(const float4*)(ap);
            float4 a1 = *(const float4*)(ap + 4);
            A2[ks*4+0] = f32x2{a0.x, a0.y};
            A2[ks*4+1] = f32x2{a0.z, a0.w};
            A2[ks*4+2] = f32x2{a1.x, a1.y};
            A2[ks*4+3] = f32x2{a1.z, a1.w};
        }

        // current e values; issue next nl's e loads
        float ev[4];
#pragma unroll
        for (int c = 0; c < 4; ++c) ev[c] = evc[c];
        if (nl < NG - 1) {
            const float* egn = edge + (size_t)(bn + 1) * (NN - 1);
#pragma unroll
            for (int c = 0; c < 4; ++c) {
                int m = c * 64 + w * 16 + lo16;
                evc[c] = egn[m < NN - 1 ? m : NN - 2];
            }
        }

        // C-slice register double buffer
        uint4 q0, q1, q2;
        {
            int m = w * 16 + lo16;
            int j = m + (m >= n);
            const unsigned short* crow = &sC[j * CPAD + hi * 8];
            q0 = *(const uint4*)(crow);
            q1 = *(const uint4*)(crow + 32);
            q2 = *(const uint4*)(crow + 64);
        }

#pragma unroll
        for (int chunk = 0; chunk < 4; ++chunk) {
            uint4 n0q, n1q, n2q;
            if (chunk < 3) {
                int mn = (chunk + 1) * 64 + w * 16 + lo16;
                int jn = mn + (mn >= n);
                if (chunk + 1 == 3) jn = (jn > 255) ? 255 : jn;
                const unsigned short* crow = &sC[jn * CPAD + hi * 8];
                n0q = *(const uint4*)(crow);
                n1q = *(const uint4*)(crow + 32);
                n2q = *(const uint4*)(crow + 64);
            }

            f32x2 e2 = f32x2{ev[chunk], ev[chunk]};
            uint4 qs[3] = {q0, q1, q2};

            short8 af[3];
#pragma unroll
            for (int ks = 0; ks < 3; ++ks) {
                unsigned uu[4] = {qs[ks].x, qs[ks].y, qs[ks].z, qs[ks].w};
                unsigned ro[4];
#pragma unroll
                for (int p = 0; p < 4; ++p) {
                    f32x2 c;
                    c.x = __uint_as_float(uu[p] << 16);
                    c.y = __uint_as_float(uu[p] & 0xFFFF0000u);
                    f32x2 s = pk_add(A2[ks*4+p], c);
                    f32x2 h = pk_fma(e2, W2p[ks*4+p], s);
                    ro[p] = pack_bf16(fmaxf(h.x, 0.f), fmaxf(h.y, 0.f));
                }
                union { unsigned u[4]; short8 s8; } cv;
                cv.u[0] = ro[0]; cv.u[1] = ro[1]; cv.u[2] = ro[2]; cv.u[3] = ro[3];
                af[ks] = cv.s8;
            }

            // invalid slot: m=255 -> row lo16==15 of wave 3, chunk 3 only
            if (chunk == 3 && w == 3 && lo16 == 15) {
                af[0] = (short8)0; af[1] = (short8)0; af[2] = (short8)0;
            }

            f32x4 acc[4] = {{0.f,0.f,0.f,0.f},{0.f,0.f,0.f,0.f},
                            {0.f,0.f,0.f,0.f},{0.f,0.f,0.f,0.f}};
#pragma unroll
            for (int ks = 0; ks < 3; ++ks)
#pragma unroll
                for (int nt = 0; nt < 4; ++nt)
                    acc[nt] = __builtin_amdgcn_mfma_f32_16x16x32_bf16(
                        af[ks], bf[nt][ks], acc[nt], 0, 0, 0);

#pragma unroll
            for (int nt = 0; nt < 4; ++nt)
#pragma unroll
                for (int r4 = 0; r4 < 4; ++r4) {
                    float arg = fmaf(acc[nt][r4], TWO_LOG2E, c2[nt]);
                    Rs[nl][nt] += RCPF(1.f + EXP2F(arg));
                }

            if (chunk < 3) { q0 = n0q; q1 = n1q; q2 = n2q; }
        }

        // invalid slot correction (D-row 15 = lanes hi==3, wave 3)
        if (w == 3 && hi == 3) {
#pragma unroll
            for (int nt = 0; nt < 4; ++nt) Rs[nl][nt] += corr[nt];
        }
    }

    // ---- final reduction: overlay on sC (all sC reads are done) ----
    __syncthreads();
    float* s_red = (float*)sC;   // [NG][4 waves][64] = 4 KB
#pragma unroll
    for (int nl = 0; nl < NG; ++nl)
#pragma unroll
        for (int nt = 0; nt < 4; ++nt) {
            float v = Rs[nl][nt];
            v += __shfl_xor(v, 16);
            v += __shfl_xor(v, 32);
            Rs[nl][nt] = v;
        }
    if (hi == 0) {
#pragma unroll
        for (int nl = 0; nl < NG; ++nl)
#pragma unroll
            for (int nt = 0; nt < 4; ++nt)
                s_red[(nl * 4 + w) * 64 + nt * 16 + lo16] = Rs[nl][nt];
    }
    __syncthreads();
    {
        int onl = tid >> 6, oo = tid & 63;   // 256 threads = 4 nl x 64 cols
        float t = s_red[(onl * 4 + 0) * 64 + oo] + s_red[(onl * 4 + 1) * 64 + oo]
                + s_red[(onl * 4 + 2) * 64 + oo] + s_red[(onl * 4 + 3) * 64 + oo];
        out[(size_t)((b << 8) + n0 + onl) * FOUT + oo] = fmaf(-2.f, t, 256.f);
    }
}

extern "C" void kernel_launch(void* const* d_in, const int* in_sizes, int n_in,
                              void* d_out, int out_size, void* d_ws, size_t ws_size,
                              hipStream_t stream) {
    const float* inp_node = (const float*)d_in[0];  // (8,256,64)
    const float* inp_edge = (const float*)d_in[1];  // (8,256,255)
    const float* W1       = (const float*)d_in[2];  // (129,96)
    const float* b1       = (const float*)d_in[3];  // (96,)
    const float* W2       = (const float*)d_in[4];  // (96,64)
    const float* b2       = (const float*)d_in[5];  // (64,)
    float* out            = (float*)d_out;          // (8,256,64)

    // single fused kernel; d_ws unused
    edge_fused<<<BATCH * (NN / NG), 256, 0, stream>>>(
        inp_node, inp_edge, W1, b1, W2, b2, out);
}